// Round 11
// baseline (28.919 us; speedup 1.0000x reference)
//
#include <hip/hip_runtime.h>

// PerturbedTopK: per (b,n) row of d=1024, top-k (k=102) indices of
// x[b] + sigma*noise[b,n], sorted ascending; out[b, rank, idx] += 1/n.
//
// R11: two-phase.
//  Phase A (select): one wave per TWO rows, sequentially pipelined:
//    issue x (shared!) + both noise rows' loads upfront (48 loads in
//    flight), then search+scatter row0 while row1's data lands, then
//    row1 with zero load stall. Breaks the phase-synchronized-wave
//    latency exposure (waves all stalled on loads simultaneously).
//    n_samples is a template constant -> div by 250 is magic-mul.
//    Stride-64 ownership (lane owns j*64+lane); 6-bound statistical
//    grid + interpolated/midpoint probe pairs (packed counts, DPP
//    trees); exact bracket invariant c(lo)>=K>c(hi); ballot+mbcnt ranks.
//  Phase B (hist): 4-rank-group LDS histogram (R9, unchanged).

#define D_DIM 1024
#define K_SEL 102
#define K_PAD 104   // ws record stride in u16; multiple of 8 -> aligned u64 groups
#define RPB 4       // ranks per hist block
#define SIGMA 0.05f
#define WAVES_PER_BLOCK 4
#define BLOCK (WAVES_PER_BLOCK * 64)
#define SLOTS 16    // D_DIM / 64 elements per lane

__device__ __forceinline__ unsigned int float_to_key(float f) {
    unsigned int u = __float_as_uint(f);
    return (u & 0x80000000u) ? ~u : (u | 0x80000000u);  // larger float -> larger uint
}

__device__ __forceinline__ unsigned int mbcnt64(unsigned long long m) {
    return __builtin_amdgcn_mbcnt_hi((unsigned int)(m >> 32),
           __builtin_amdgcn_mbcnt_lo((unsigned int)m, 0u));
}

// wave64 sum via DPP row_shr tree + row broadcasts; total in lane 63.
__device__ __forceinline__ unsigned int wave_sum_u32(unsigned int v) {
    v += (unsigned int)__builtin_amdgcn_update_dpp(0, (int)v, 0x111, 0xF, 0xF, false); // row_shr:1
    v += (unsigned int)__builtin_amdgcn_update_dpp(0, (int)v, 0x112, 0xF, 0xF, false); // row_shr:2
    v += (unsigned int)__builtin_amdgcn_update_dpp(0, (int)v, 0x114, 0xF, 0xF, false); // row_shr:4
    v += (unsigned int)__builtin_amdgcn_update_dpp(0, (int)v, 0x118, 0xF, 0xF, false); // row_shr:8
    v += (unsigned int)__builtin_amdgcn_update_dpp(0, (int)v, 0x142, 0xA, 0xF, false); // row_bcast:15
    v += (unsigned int)__builtin_amdgcn_update_dpp(0, (int)v, 0x143, 0xC, 0xF, false); // row_bcast:31
    return (unsigned int)__builtin_amdgcn_readlane((int)v, 63);
}

// packed counts of {key >= m1} and {key >= m2}<<16 across the wave's 1024 elems
__device__ __forceinline__ unsigned int count_ge2(const unsigned int* key,
                                                  unsigned int m1, unsigned int m2) {
    unsigned int a = 0, b = 0;
    #pragma unroll
    for (int j = 0; j < SLOTS; ++j) {
        a += (key[j] >= m1) ? 1u : 0u;
        b += (key[j] >= m2) ? 1u : 0u;
    }
    return wave_sum_u32(a | (b << 16));
}

// Full per-row select: grid + bracket search + classify + rank + scatter.
// key: this wave's 1024 elements (lane owns j*64+lane). Proven R10 logic.
template <bool USE_WS>
__device__ __forceinline__ void select_row(const unsigned int* key, int lane,
                                           unsigned short* wb, float* orow,
                                           float inv_n) {
    // ---- initial 6-bound grid (one pass, three packed DPP reductions) ----
    // threshold order-stat ~ N(1.284, 0.053); grid covers ~±4 sigma.
    const unsigned int B1 = float_to_key(1.07f);
    const unsigned int B2 = float_to_key(1.17f);
    const unsigned int B3 = float_to_key(1.25f);
    const unsigned int B4 = float_to_key(1.32f);
    const unsigned int B5 = float_to_key(1.40f);
    const unsigned int B6 = float_to_key(1.50f);
    unsigned int pA = 0, pB = 0, pC = 0;
    #pragma unroll
    for (int j = 0; j < SLOTS; ++j) {
        pA += ((key[j] >= B1) ? 1u : 0u) + ((key[j] >= B2) ? 0x10000u : 0u);
        pB += ((key[j] >= B3) ? 1u : 0u) + ((key[j] >= B4) ? 0x10000u : 0u);
        pC += ((key[j] >= B5) ? 1u : 0u) + ((key[j] >= B6) ? 0x10000u : 0u);
    }
    const unsigned int tA = wave_sum_u32(pA);
    const unsigned int tB = wave_sum_u32(pB);
    const unsigned int tC = wave_sum_u32(pC);
    const unsigned int c1 = tA & 0xFFFFu, c2 = tA >> 16;
    const unsigned int c3 = tB & 0xFFFFu, c4 = tB >> 16;
    const unsigned int c5 = tC & 0xFFFFu, c6 = tC >> 16;

    unsigned int lo, hi, c_lo, c_hi;
    if (c6 >= K_SEL)      { lo = B6; c_lo = c6;    hi = 0xFFFFFFFFu; c_hi = 0u; }
    else if (c5 >= K_SEL) { lo = B5; c_lo = c5;    hi = B6; c_hi = c6; }
    else if (c4 >= K_SEL) { lo = B4; c_lo = c4;    hi = B5; c_hi = c5; }
    else if (c3 >= K_SEL) { lo = B3; c_lo = c3;    hi = B4; c_hi = c4; }
    else if (c2 >= K_SEL) { lo = B2; c_lo = c2;    hi = B3; c_hi = c3; }
    else if (c1 >= K_SEL) { lo = B1; c_lo = c1;    hi = B2; c_hi = c2; }
    else                  { lo = 0u; c_lo = D_DIM; hi = B1; c_hi = c1; }
    // key==0 (-NaN) and key==0xFFFFFFFF (+NaN) unreachable from finite inputs.

    // ---- bracket search: interpolated + midpoint probe pair per pass ----
    while (c_lo != K_SEL && (hi - lo) > 1u) {
        const unsigned int span = hi - lo;
        unsigned int o1 = (unsigned int)((float)(c_lo - K_SEL) * (float)span /
                                         (float)(c_lo - c_hi));
        unsigned int o2 = span >> 1;
        if (o1 < 1u) o1 = 1u;
        if (o1 > span - 1u) o1 = span - 1u;
        const unsigned int mA = lo + (o1 < o2 ? o1 : o2);
        const unsigned int mB = lo + (o1 < o2 ? o2 : o1);   // mA <= mB, in (lo,hi)

        const unsigned int s = count_ge2(key, mA, mB);
        const unsigned int cA = s & 0xFFFFu;
        const unsigned int cB = s >> 16;

        if (cB >= K_SEL)      { lo = mB; c_lo = cB; }
        else if (cA >= K_SEL) { lo = mA; c_lo = cA; hi = mB; c_hi = cB; }
        else                  { hi = mA; c_hi = cA; }
    }

    unsigned int SEL_B, kkf, tieK;
    if (c_lo == K_SEL) { SEL_B = lo; kkf = 0u;           tieK = 0u; } // unique top-K set
    else               { SEL_B = hi; kkf = K_SEL - c_hi; tieK = lo; } // hi==lo+1, T==lo

    // ---- rank + scatter, index order = (j, lane) ----
    if (kkf == 0u) {
        unsigned int base = 0u;
        #pragma unroll
        for (int j = 0; j < SLOTS; ++j) {
            const bool p = key[j] >= SEL_B;
            const unsigned long long sb = __ballot(p);
            if (p) {
                const unsigned int rank = base + mbcnt64(sb);
                const unsigned int idx  = (unsigned int)(j * 64) + lane;
                if (USE_WS) wb[rank] = (unsigned short)idx;
                else atomicAdd(orow + (size_t)rank * D_DIM + idx, inv_n);
            }
            base += (unsigned int)__popcll(sb);
        }
    } else {
        unsigned int gt_base = 0u, eq_base = 0u;
        #pragma unroll
        for (int j = 0; j < SLOTS; ++j) {
            const bool pg = key[j] >= SEL_B;
            const bool pe = key[j] == tieK;
            const unsigned long long sb = __ballot(pg);
            const unsigned long long ab = __ballot(pe);
            const unsigned int gtp = gt_base + mbcnt64(sb);
            const unsigned int eqp = eq_base + mbcnt64(ab);
            const unsigned int idx = (unsigned int)(j * 64) + lane;
            if (pg) {
                const unsigned int rank = gtp + (eqp < kkf ? eqp : kkf);
                if (USE_WS) wb[rank] = (unsigned short)idx;
                else atomicAdd(orow + (size_t)rank * D_DIM + idx, inv_n);
            } else if (pe && eqp < kkf) {
                if (USE_WS) wb[gtp + eqp] = (unsigned short)idx;
                else atomicAdd(orow + (size_t)(gtp + eqp) * D_DIM + idx, inv_n);
            }
            gt_base += (unsigned int)__popcll(sb);
            eq_base += (unsigned int)__popcll(ab);
        }
    }
}

// ---------------- Phase A: paired-row pipelined select ----------------
// NS must be EVEN (both rows of a pair share one batch). NS known at
// compile time -> bb = r0/NS is a magic-multiply, not a runtime div.
template <bool USE_WS, int NS>
__global__ __launch_bounds__(BLOCK)
void ptopk_select2(const float* __restrict__ x,
                   const float* __restrict__ noise,
                   unsigned short* __restrict__ ws_idx,  // [b][NS][K_PAD]
                   float* __restrict__ out,              // fallback path only
                   float inv_n, int npairs) {
    const int wid  = threadIdx.x >> 6;
    const int lane = threadIdx.x & 63;
    const int pair = blockIdx.x * WAVES_PER_BLOCK + wid;
    if (pair >= npairs) return;                  // wave-uniform
    const int r0 = pair * 2;
    const int bb = r0 / NS;                      // compile-time magic mul
    const int ss = r0 - bb * NS;

    const float* xb  = x + (size_t)bb * D_DIM + lane;
    const float* nb0 = noise + (size_t)r0 * D_DIM + lane;
    const float* nb1 = nb0 + D_DIM;

    // issue ALL loads upfront: x (shared by both rows) + both noise rows.
    // Row1's loads stay in flight across row0's entire search+scatter.
    float xv[SLOTS], f0[SLOTS], f1[SLOTS];
    #pragma unroll
    for (int j = 0; j < SLOTS; ++j) {
        xv[j] = xb[j * 64];
        f0[j] = nb0[j * 64];
        f1[j] = nb1[j * 64];
    }

    unsigned short* wb = ws_idx + ((size_t)bb * NS + ss) * K_PAD;
    float* orow = out + (size_t)bb * (K_SEL * D_DIM);

    unsigned int key[SLOTS];
    #pragma unroll
    for (int j = 0; j < SLOTS; ++j) key[j] = float_to_key(fmaf(f0[j], SIGMA, xv[j]));
    select_row<USE_WS>(key, lane, wb, orow, inv_n);

    #pragma unroll
    for (int j = 0; j < SLOTS; ++j) key[j] = float_to_key(fmaf(f1[j], SIGMA, xv[j]));
    select_row<USE_WS>(key, lane, wb + K_PAD, orow, inv_n);
}

// generic single-row fallback (odd n_samples etc.)
template <bool USE_WS>
__global__ __launch_bounds__(BLOCK)
void ptopk_select1(const float* __restrict__ x,
                   const float* __restrict__ noise,
                   unsigned short* __restrict__ ws_idx,
                   float* __restrict__ out,
                   int n_samples, float inv_n, int nrows) {
    const int wid  = threadIdx.x >> 6;
    const int lane = threadIdx.x & 63;
    const int row  = blockIdx.x * WAVES_PER_BLOCK + wid;
    if (row >= nrows) return;
    const int bb = row / n_samples;
    const int ss = row - bb * n_samples;

    const float* xb = x + (size_t)bb * D_DIM + lane;
    const float* nb = noise + (size_t)row * D_DIM + lane;
    unsigned int key[SLOTS];
    #pragma unroll
    for (int j = 0; j < SLOTS; ++j)
        key[j] = float_to_key(fmaf(nb[j * 64], SIGMA, xb[j * 64]));

    unsigned short* wb = ws_idx + ((size_t)bb * n_samples + ss) * K_PAD;
    float* orow = out + (size_t)bb * (K_SEL * D_DIM);
    select_row<USE_WS>(key, lane, wb, orow, inv_n);
}

// ---------------- Phase B: 4-rank histogram + coalesced write ----------------
__global__ __launch_bounds__(256)
void ptopk_hist(const unsigned short* __restrict__ ws_idx,  // [b][n_samples][K_PAD]
                float* __restrict__ out,                    // [b][K_SEL][D_DIM]
                int n_samples, float inv_n) {
    __shared__ unsigned int cnt[RPB][D_DIM];   // 16 KB
    const int tid  = threadIdx.x;
    const int ngrp = K_PAD / RPB;              // 26
    const int b_   = blockIdx.x / ngrp;
    const int g_   = blockIdx.x - b_ * ngrp;
    const int r0   = g_ * RPB;

    uint4* cz = reinterpret_cast<uint4*>(&cnt[0][0]);
    #pragma unroll
    for (int c = 0; c < (RPB * D_DIM) / (4 * 256); ++c)
        cz[c * 256 + tid] = make_uint4(0u, 0u, 0u, 0u);
    __syncthreads();

    for (int s = tid; s < n_samples; s += 256) {
        const unsigned long long v = *reinterpret_cast<const unsigned long long*>(
            ws_idx + ((size_t)b_ * n_samples + s) * K_PAD + r0);
        #pragma unroll
        for (int e = 0; e < RPB; ++e) {
            // pad ranks (>=K_SEL) carry poison garbage: clamp into range; their
            // counts land in hist rows that are never written out.
            const unsigned int idx = (unsigned int)((v >> (16 * e)) & 0xFFFFu) & (D_DIM - 1u);
            atomicAdd(&cnt[e][idx], 1u);
        }
    }
    __syncthreads();

    const int i = tid * 4;
    #pragma unroll
    for (int e = 0; e < RPB; ++e) {
        const int rank = r0 + e;
        if (rank < K_SEL) {
            float4* dst = reinterpret_cast<float4*>(out + ((size_t)b_ * K_SEL + rank) * D_DIM);
            dst[tid] = make_float4(cnt[e][i] * inv_n, cnt[e][i + 1] * inv_n,
                                   cnt[e][i + 2] * inv_n, cnt[e][i + 3] * inv_n);
        }
    }
}

__global__ __launch_bounds__(256)
void zero_kernel(float4* __restrict__ p, int n4) {
    const int i = blockIdx.x * 256 + threadIdx.x;
    if (i < n4) p[i] = make_float4(0.f, 0.f, 0.f, 0.f);
}

extern "C" void kernel_launch(void* const* d_in, const int* in_sizes, int n_in,
                              void* d_out, int out_size, void* d_ws, size_t ws_size,
                              hipStream_t stream) {
    const float* x     = (const float*)d_in[0];
    const float* noise = (const float*)d_in[1];
    float* out = (float*)d_out;

    const int d = D_DIM;                       // 1024
    const int b = in_sizes[0] / d;             // 32
    const int n = in_sizes[1] / in_sizes[0];   // 250
    const int rows = b * n;                    // 8000
    const float inv_n = 1.0f / (float)n;

    const size_t ws_needed = (size_t)b * n * K_PAD * sizeof(unsigned short);
    if (ws_size >= ws_needed) {
        unsigned short* ws_idx = (unsigned short*)d_ws;
        if (n == 250) {
            const int npairs = rows / 2;
            const int grid = (npairs + WAVES_PER_BLOCK - 1) / WAVES_PER_BLOCK;
            ptopk_select2<true, 250><<<grid, BLOCK, 0, stream>>>(
                x, noise, ws_idx, out, inv_n, npairs);
        } else {
            const int grid = (rows + WAVES_PER_BLOCK - 1) / WAVES_PER_BLOCK;
            ptopk_select1<true><<<grid, BLOCK, 0, stream>>>(
                x, noise, ws_idx, out, n, inv_n, rows);
        }
        ptopk_hist<<<b * (K_PAD / RPB), 256, 0, stream>>>(ws_idx, out, n, inv_n);
    } else {
        // fallback: atomic-scatter path
        const int n4 = out_size / 4;
        zero_kernel<<<(n4 + 255) / 256, 256, 0, stream>>>((float4*)out, n4);
        const int grid = (rows + WAVES_PER_BLOCK - 1) / WAVES_PER_BLOCK;
        ptopk_select1<false><<<grid, BLOCK, 0, stream>>>(
            x, noise, nullptr, out, n, inv_n, rows);
    }
}

// Round 13
// 24.998 us; speedup vs baseline: 1.1569x; 1.1569x over previous
//
#include <hip/hip_runtime.h>

// PerturbedTopK: per (b,n) row of d=1024, top-k (k=102) indices of
// x[b] + sigma*noise[b,n], sorted ascending; out[b, rank, idx] += 1/n.
//
// R13 = R12 with the nontemporal-store compile fix (native ext_vector_type
// instead of HIP_vector_type float4).
//  - WAVES_PER_BLOCK 2: smaller blocks stagger wave start times per CU,
//    de-synchronizing load-stall/probe phases of co-resident waves.
//  - nontemporal stores for phase-B's write-once 13.4MB output.
//
//  Phase A (select): one wave per row. float4 loads, 6-bound packed
//    statistical grid, interpolated+midpoint probe pairs (packed 16-bit
//    counts, DPP trees), exact bracket invariant c(lo)>=K>c(hi). Stores
//    selected u16 index at ws[b][sample][rank], record stride K_PAD=104.
//  Phase B (hist): one block per (b, 4-rank group): each thread loads ONE
//    aligned u64 = 4 ranks of one sample, LDS hist[4][1024], coalesced
//    float4 row writes (writes every cell -> no zeroing pass needed).

#define D_DIM 1024
#define K_SEL 102
#define K_PAD 104   // ws record stride in u16; multiple of 8 -> aligned u64 groups
#define RPB 4       // ranks per hist block
#define SIGMA 0.05f
#define WAVES_PER_BLOCK 2
#define BLOCK (WAVES_PER_BLOCK * 64)
#define SLOTS 16    // D_DIM / 64 elements per lane

typedef float f32x4 __attribute__((ext_vector_type(4)));   // native vec for NT store

__device__ __forceinline__ unsigned int float_to_key(float f) {
    unsigned int u = __float_as_uint(f);
    return (u & 0x80000000u) ? ~u : (u | 0x80000000u);  // larger float -> larger uint
}

// wave64 inclusive scan (DPP row_shr tree + masked row broadcasts).
__device__ __forceinline__ unsigned int wave_incl_scan(unsigned int v) {
    v += (unsigned int)__builtin_amdgcn_update_dpp(0, (int)v, 0x111, 0xF, 0xF, false); // row_shr:1
    v += (unsigned int)__builtin_amdgcn_update_dpp(0, (int)v, 0x112, 0xF, 0xF, false); // row_shr:2
    v += (unsigned int)__builtin_amdgcn_update_dpp(0, (int)v, 0x114, 0xF, 0xF, false); // row_shr:4
    v += (unsigned int)__builtin_amdgcn_update_dpp(0, (int)v, 0x118, 0xF, 0xF, false); // row_shr:8
    v += (unsigned int)__builtin_amdgcn_update_dpp(0, (int)v, 0x142, 0xA, 0xF, false); // row_bcast:15
    v += (unsigned int)__builtin_amdgcn_update_dpp(0, (int)v, 0x143, 0xC, 0xF, false); // row_bcast:31
    return v;
}
__device__ __forceinline__ unsigned int wave_sum_u32(unsigned int v) {
    return (unsigned int)__builtin_amdgcn_readlane((int)wave_incl_scan(v), 63);
}

// packed counts of {key >= m1} and {key >= m2}<<16 across the wave's 1024 elems
__device__ __forceinline__ unsigned int count_ge2(const unsigned int* key,
                                                  unsigned int m1, unsigned int m2) {
    unsigned int a = 0, b = 0;
    #pragma unroll
    for (int j = 0; j < SLOTS; ++j) {
        a += (key[j] >= m1) ? 1u : 0u;
        b += (key[j] >= m2) ? 1u : 0u;
    }
    return wave_sum_u32(a | (b << 16));
}

// ---------------- Phase A: select + index store ----------------
template <bool USE_WS>
__global__ __launch_bounds__(BLOCK)
void ptopk_select(const float* __restrict__ x,
                  const float* __restrict__ noise,
                  unsigned short* __restrict__ ws_idx,  // [b][n_samples][K_PAD]
                  float* __restrict__ out,              // fallback path only
                  int n_samples, float inv_n, int nrows) {
    const int wid  = threadIdx.x >> 6;
    const int lane = threadIdx.x & 63;
    const int row  = blockIdx.x * WAVES_PER_BLOCK + wid;
    if (row >= nrows) return;                    // wave-uniform
    const int bb = row / n_samples;
    const int ss = row - bb * n_samples;

    const float4* nrow =
        reinterpret_cast<const float4*>(noise + (size_t)row * D_DIM + lane * SLOTS);
    const float4* xrow =
        reinterpret_cast<const float4*>(x + (size_t)bb * D_DIM + lane * SLOTS);

    unsigned int key[SLOTS];
    #pragma unroll
    for (int c = 0; c < 4; ++c) {
        const float4 nv = nrow[c];
        const float4 xv = xrow[c];
        key[c*4+0] = float_to_key(fmaf(nv.x, SIGMA, xv.x));
        key[c*4+1] = float_to_key(fmaf(nv.y, SIGMA, xv.y));
        key[c*4+2] = float_to_key(fmaf(nv.z, SIGMA, xv.z));
        key[c*4+3] = float_to_key(fmaf(nv.w, SIGMA, xv.w));
    }

    // ---- initial 6-bound grid (one pass, three packed DPP reductions) ----
    // threshold order-stat ~ N(1.284, 0.053); grid covers ~±4 sigma.
    // Outlier rows fall into the generic outer brackets (exact, just slower).
    const unsigned int B1 = float_to_key(1.07f);
    const unsigned int B2 = float_to_key(1.17f);
    const unsigned int B3 = float_to_key(1.25f);
    const unsigned int B4 = float_to_key(1.32f);
    const unsigned int B5 = float_to_key(1.40f);
    const unsigned int B6 = float_to_key(1.50f);
    unsigned int pA = 0, pB = 0, pC = 0;
    #pragma unroll
    for (int j = 0; j < SLOTS; ++j) {
        pA += ((key[j] >= B1) ? 1u : 0u) + ((key[j] >= B2) ? 0x10000u : 0u);
        pB += ((key[j] >= B3) ? 1u : 0u) + ((key[j] >= B4) ? 0x10000u : 0u);
        pC += ((key[j] >= B5) ? 1u : 0u) + ((key[j] >= B6) ? 0x10000u : 0u);
    }
    const unsigned int tA = wave_sum_u32(pA);
    const unsigned int tB = wave_sum_u32(pB);
    const unsigned int tC = wave_sum_u32(pC);
    const unsigned int c1 = tA & 0xFFFFu, c2 = tA >> 16;
    const unsigned int c3 = tB & 0xFFFFu, c4 = tB >> 16;
    const unsigned int c5 = tC & 0xFFFFu, c6 = tC >> 16;

    unsigned int lo, hi, c_lo, c_hi;
    if (c6 >= K_SEL)      { lo = B6; c_lo = c6;    hi = 0xFFFFFFFFu; c_hi = 0u; }
    else if (c5 >= K_SEL) { lo = B5; c_lo = c5;    hi = B6; c_hi = c6; }
    else if (c4 >= K_SEL) { lo = B4; c_lo = c4;    hi = B5; c_hi = c5; }
    else if (c3 >= K_SEL) { lo = B3; c_lo = c3;    hi = B4; c_hi = c4; }
    else if (c2 >= K_SEL) { lo = B2; c_lo = c2;    hi = B3; c_hi = c3; }
    else if (c1 >= K_SEL) { lo = B1; c_lo = c1;    hi = B2; c_hi = c2; }
    else                  { lo = 0u; c_lo = D_DIM; hi = B1; c_hi = c1; }
    // key==0 (-NaN) and key==0xFFFFFFFF (+NaN) are unreachable from finite
    // inputs, so c(0)=D_DIM and c(MAX)=0 hold without counting.

    // ---- bracket search: interpolated + midpoint probe pair per pass ----
    // Invariant: c_lo = #{key>=lo} >= K_SEL > c_hi = #{key>=hi}; strict
    // shrink each pass (midpoint safeguards) -> terminates.
    while (c_lo != K_SEL && (hi - lo) > 1u) {
        const unsigned int span = hi - lo;
        unsigned int o1 = (unsigned int)((float)(c_lo - K_SEL) * (float)span /
                                         (float)(c_lo - c_hi));
        unsigned int o2 = span >> 1;
        if (o1 < 1u) o1 = 1u;
        if (o1 > span - 1u) o1 = span - 1u;
        const unsigned int mA = lo + (o1 < o2 ? o1 : o2);
        const unsigned int mB = lo + (o1 < o2 ? o2 : o1);   // mA <= mB, both in (lo,hi)

        const unsigned int s = count_ge2(key, mA, mB);
        const unsigned int cA = s & 0xFFFFu;
        const unsigned int cB = s >> 16;

        if (cB >= K_SEL)      { lo = mB; c_lo = cB; }
        else if (cA >= K_SEL) { lo = mA; c_lo = cA; hi = mB; c_hi = cB; }
        else                  { hi = mA; c_hi = cA; }
    }

    // ---- end state ----
    unsigned int SEL_B, kkf, tieK;
    if (c_lo == K_SEL) { SEL_B = lo; kkf = 0u;           tieK = 0u; } // unique top-K set
    else               { SEL_B = hi; kkf = K_SEL - c_hi; tieK = lo; } // hi==lo+1, T==lo

    unsigned int sel = 0u, alive = 0u;
    #pragma unroll
    for (int j = 0; j < SLOTS; ++j) {
        sel   |= (key[j] >= SEL_B) ? (1u << j) : 0u;
        alive |= (key[j] == tieK)  ? (1u << j) : 0u;
    }

    // ---- ranks: exclusive prefix over lanes of packed (gt<<16 | eq) ----
    const unsigned int mine =
        ((unsigned int)__popc(sel) << 16) | (unsigned int)__popc(alive);
    unsigned int run = wave_incl_scan(mine) - mine;  // exclusive prefix (packed)

    unsigned short* wb = ws_idx + ((size_t)bb * n_samples + ss) * K_PAD;
    float* orow = out + (size_t)bb * (K_SEL * D_DIM);
    const int base_i = lane * SLOTS;
    unsigned int both = sel | alive;
    while (both) {
        const int j = __builtin_ctz(both);
        both &= both - 1u;
        const unsigned int gtp = run >> 16;
        const unsigned int eqp = run & 0xFFFFu;
        if (sel & (1u << j)) {
            const unsigned int rank = gtp + (eqp < kkf ? eqp : kkf);
            if (USE_WS) wb[rank] = (unsigned short)(base_i + j);
            else atomicAdd(orow + (size_t)rank * D_DIM + (base_i + j), inv_n);
            run += 0x10000u;
        } else {
            if (eqp < kkf) {
                if (USE_WS) wb[gtp + eqp] = (unsigned short)(base_i + j);
                else atomicAdd(orow + (size_t)(gtp + eqp) * D_DIM + (base_i + j), inv_n);
            }
            run += 1u;
        }
    }
}

// ---------------- Phase B: 4-rank histogram + coalesced write ----------------
__global__ __launch_bounds__(256)
void ptopk_hist(const unsigned short* __restrict__ ws_idx,  // [b][n_samples][K_PAD]
                float* __restrict__ out,                    // [b][K_SEL][D_DIM]
                int n_samples, float inv_n) {
    __shared__ unsigned int cnt[RPB][D_DIM];   // 16 KB
    const int tid  = threadIdx.x;
    const int ngrp = K_PAD / RPB;              // 26
    const int b_   = blockIdx.x / ngrp;
    const int g_   = blockIdx.x - b_ * ngrp;
    const int r0   = g_ * RPB;

    uint4* cz = reinterpret_cast<uint4*>(&cnt[0][0]);
    #pragma unroll
    for (int c = 0; c < (RPB * D_DIM) / (4 * 256); ++c)
        cz[c * 256 + tid] = make_uint4(0u, 0u, 0u, 0u);
    __syncthreads();

    // one aligned u64 per sample = this block's 4 ranks of that sample.
    // byte offset = 208*rec + 8*g_  -> 8-aligned (208 = 16*13).
    for (int s = tid; s < n_samples; s += 256) {
        const unsigned long long v = *reinterpret_cast<const unsigned long long*>(
            ws_idx + ((size_t)b_ * n_samples + s) * K_PAD + r0);
        #pragma unroll
        for (int e = 0; e < RPB; ++e) {
            // pad ranks (>=K_SEL) carry poison garbage: clamp into range; their
            // counts land in hist rows that are never written out.
            const unsigned int idx = (unsigned int)((v >> (16 * e)) & 0xFFFFu) & (D_DIM - 1u);
            atomicAdd(&cnt[e][idx], 1u);
        }
    }
    __syncthreads();

    const int i = tid * 4;
    #pragma unroll
    for (int e = 0; e < RPB; ++e) {
        const int rank = r0 + e;
        if (rank < K_SEL) {
            f32x4* dst = reinterpret_cast<f32x4*>(out + ((size_t)b_ * K_SEL + rank) * D_DIM);
            f32x4 v4;
            v4.x = cnt[e][i]     * inv_n;
            v4.y = cnt[e][i + 1] * inv_n;
            v4.z = cnt[e][i + 2] * inv_n;
            v4.w = cnt[e][i + 3] * inv_n;
            __builtin_nontemporal_store(v4, &dst[tid]);   // write-once output
        }
    }
}

__global__ __launch_bounds__(256)
void zero_kernel(float4* __restrict__ p, int n4) {
    const int i = blockIdx.x * 256 + threadIdx.x;
    if (i < n4) p[i] = make_float4(0.f, 0.f, 0.f, 0.f);
}

extern "C" void kernel_launch(void* const* d_in, const int* in_sizes, int n_in,
                              void* d_out, int out_size, void* d_ws, size_t ws_size,
                              hipStream_t stream) {
    const float* x     = (const float*)d_in[0];
    const float* noise = (const float*)d_in[1];
    float* out = (float*)d_out;

    const int d = D_DIM;                       // 1024
    const int b = in_sizes[0] / d;             // 32
    const int n = in_sizes[1] / in_sizes[0];   // 250
    const int rows = b * n;                    // 8000
    const float inv_n = 1.0f / (float)n;
    const int grid = (rows + WAVES_PER_BLOCK - 1) / WAVES_PER_BLOCK;

    const size_t ws_needed = (size_t)b * n * K_PAD * sizeof(unsigned short);
    if (ws_size >= ws_needed) {
        // two-phase, atomic-free path
        unsigned short* ws_idx = (unsigned short*)d_ws;
        ptopk_select<true><<<grid, BLOCK, 0, stream>>>(x, noise, ws_idx, out,
                                                       n, inv_n, rows);
        ptopk_hist<<<b * (K_PAD / RPB), 256, 0, stream>>>(ws_idx, out, n, inv_n);
    } else {
        // fallback: atomic-scatter path
        const int n4 = out_size / 4;
        zero_kernel<<<(n4 + 255) / 256, 256, 0, stream>>>((float4*)out, n4);
        ptopk_select<false><<<grid, BLOCK, 0, stream>>>(x, noise, nullptr, out,
                                                        n, inv_n, rows);
    }
}